// Round 3
// baseline (388.898 us; speedup 1.0000x reference)
//
#include <hip/hip_runtime.h>
#include <cstdint>
#include <cstddef>

// Problem constants (B=8192, P=8192, F=256; SIGMA=1 -> denom = 2)
#define B_ROWS 8192
#define P_ROWS 8192
#define FDIM   256

// Geometry: NO LDS, NO barriers. Block = 4 independent waves; wave owns
// 32 M-rows x 256 N-cols. Both MFMA operand fragments (16x16x32 bf16) are
// 16 contiguous bytes per lane in a K-contiguous layout -> load A AND B
// straight from global (L1/L2-resident bf16 planes). Waves drift freely;
// latency hiding comes from 12 waves/CU of independent dataflow instead of
// barrier-coupled LDS staging (round-1 lesson: staging BW was never the
// limiter; barrier-exposed latency was).
#define MB     128              // M rows per block (4 waves x 32)
#define NB     256              // N cols per block
#define NTILES 4                // 4 x 64-col MFMA tiles per block
#define NBLK   ((B_ROWS / MB) * (P_ROWS / NB))   // 64 x 32 = 2048

typedef __bf16  bf16x8  __attribute__((ext_vector_type(8)));
typedef float   floatx4 __attribute__((ext_vector_type(4)));

// round-to-nearest-even fp32 -> bf16 (inputs are finite Gaussians, no NaN path)
__device__ __forceinline__ unsigned short f2bf(float f) {
  unsigned int u = __float_as_uint(f);
  u += 0x7fffu + ((u >> 16) & 1u);
  return (unsigned short)(u >> 16);
}

// ---------------------------------------------------------------------------
// Pre-pass: convert x / prototypes to bf16 planes in ws, compute fp32 row
// norms. One wave per row (64 lanes x float4 = 256 elems).
// ---------------------------------------------------------------------------
__global__ void __launch_bounds__(64) prep_kernel(
    const float* __restrict__ x, const float* __restrict__ p,
    unsigned short* __restrict__ xbf, unsigned short* __restrict__ pbf,
    float* __restrict__ x2, float* __restrict__ p2) {
  const int row  = blockIdx.x;
  const int lane = threadIdx.x;

  const float* src;
  unsigned short* dst;
  float* nrm;
  int r;
  if (row < B_ROWS) { src = x; dst = xbf; nrm = x2; r = row; }
  else              { src = p; dst = pbf; nrm = p2; r = row - B_ROWS; }

  const float4 v = *reinterpret_cast<const float4*>(src + (size_t)r * FDIM + lane * 4);
  float s = v.x * v.x + v.y * v.y + v.z * v.z + v.w * v.w;
  #pragma unroll
  for (int o = 32; o > 0; o >>= 1) s += __shfl_down(s, o);
  if (lane == 0) nrm[r] = s;

  ushort4 pk;
  pk.x = f2bf(v.x); pk.y = f2bf(v.y); pk.z = f2bf(v.z); pk.w = f2bf(v.w);
  *reinterpret_cast<ushort4*>(dst + (size_t)r * FDIM + lane * 4) = pk;
}

// ---------------------------------------------------------------------------
// Main kernel.
//
// Fragment layouts (16x16x32 bf16, verified in rounds 0-2):
//   A: lane (lm,q) holds row lm, k = q*8..q*8+7      -> 16B global load
//   B: lane (lm,q) holds col lm, k = q*8..q*8+7      -> 16B global load
// Column permute applied at the B *load address*: for acc[i][j], lane lm
// reads proto (Nt + 4*lm + j)  ->  C col at lane lm is proto 4*lm+j  ->
// lane owns 4 contiguous output columns -> float4 nt stores, float4 p2 load.
//
// XCD swizzle (2048 blocks, %8==0, bijective): XCD x owns N-strips
// [4x, 4x+4), sweeping M fastest -> concurrent blocks on an XCD share a
// 512 KB pbf slice (L2-resident) and the same 32 KB B-tile (L1-resident
// across the block's 4 waves, which read identical B addresses).
// ---------------------------------------------------------------------------
__global__ void __launch_bounds__(256, 3) gauss_kernel(
    const unsigned short* __restrict__ xbf, const unsigned short* __restrict__ pbf,
    const float* __restrict__ x2, const float* __restrict__ p2,
    float* __restrict__ out) {
  const int t    = threadIdx.x;
  const int lane = t & 63;
  const int w    = t >> 6;        // wave 0..3
  const int lm   = lane & 15;
  const int q    = lane >> 4;     // 0..3

  const int f   = blockIdx.x;     // 0..2047
  const int xcd = f & 7;
  const int idx = f >> 3;         // 0..255
  const int bm  = idx & 63;       // M-band, fastest within XCD
  const int bn  = xcd * 4 + (idx >> 6);   // N-strip, 4 per XCD

  const int M0 = bm * MB + w * 32;
  const int N0 = bn * NB;

  // ---- A fragments in registers (64 VGPR), rows M0+lm and M0+16+lm ----
  const unsigned short* aBase = xbf + (size_t)(M0 + lm) * FDIM + q * 8;
  bf16x8 af[2][8];
  #pragma unroll
  for (int i = 0; i < 2; ++i)
    #pragma unroll
    for (int kw = 0; kw < 8; ++kw)
      af[i][kw] = *(const bf16x8*)(aBase + (size_t)i * 16 * FDIM + kw * 32);

  floatx4 x2v[2];
  #pragma unroll
  for (int i = 0; i < 2; ++i)
    x2v[i] = *(const floatx4*)&x2[M0 + i * 16 + q * 4];

  // per-lane part of the B address; (Nt + j)*FDIM + kw*32 is wave-uniform
  const unsigned short* bBase = pbf + (size_t)(4 * lm) * FDIM + q * 8;

  for (int tt = 0; tt < NTILES; ++tt) {
    const int Nt = N0 + tt * 64;

    floatx4 acc[2][4] = {};
    #pragma unroll
    for (int kw = 0; kw < 8; ++kw) {
      bf16x8 bfr[4];
      #pragma unroll
      for (int j = 0; j < 4; ++j)
        bfr[j] = *(const bf16x8*)(bBase + (size_t)(Nt + j) * FDIM + kw * 32);
      #pragma unroll
      for (int i = 0; i < 2; ++i)
        #pragma unroll
        for (int j = 0; j < 4; ++j)
          acc[i][j] = __builtin_amdgcn_mfma_f32_16x16x32_bf16(af[i][kw], bfr[j], acc[i][j], 0, 0, 0);
    }

    // epilogue: d2 -> exp(-sqrt(d2)/2), float4 nt stores (4 rows x 256 B
    // contiguous per store instruction)
    const floatx4 p2r = *(const floatx4*)&p2[Nt + 4 * lm];
    #pragma unroll
    for (int i = 0; i < 2; ++i) {
      #pragma unroll
      for (int v = 0; v < 4; ++v) {
        floatx4 res;
        #pragma unroll
        for (int j = 0; j < 4; ++j) {
          float d2 = x2v[i][v] + p2r[j] - 2.0f * acc[i][j][v];
          d2 = fmaxf(d2, 0.0f);
          res[j] = __expf(-0.5f * sqrtf(d2));   // denom = 2*sigma^2 = 2
        }
        __builtin_nontemporal_store(
            res, (floatx4*)(out + (size_t)(M0 + i * 16 + q * 4 + v) * P_ROWS + Nt + 4 * lm));
      }
    }
  }
}

// ---------------------------------------------------------------------------
extern "C" void kernel_launch(void* const* d_in, const int* in_sizes, int n_in,
                              void* d_out, int out_size, void* d_ws, size_t ws_size,
                              hipStream_t stream) {
  const float* x = (const float*)d_in[0];
  const float* p = (const float*)d_in[1];
  float* out = (float*)d_out;

  // ws layout: xbf (4 MiB) | pbf (4 MiB) | x2 (32 KiB) | p2 (32 KiB)
  char* ws = (char*)d_ws;
  unsigned short* xbf = (unsigned short*)ws;
  unsigned short* pbf = (unsigned short*)(ws + (size_t)B_ROWS * FDIM * 2);
  float* x2 = (float*)(ws + (size_t)(B_ROWS + P_ROWS) * FDIM * 2);
  float* p2 = x2 + B_ROWS;

  prep_kernel<<<dim3(B_ROWS + P_ROWS), dim3(64), 0, stream>>>(x, p, xbf, pbf, x2, p2);

  gauss_kernel<<<dim3(NBLK), dim3(256), 0, stream>>>(xbf, pbf, x2, p2, out);
}

// Round 4
// 316.789 us; speedup vs baseline: 1.2276x; 1.2276x over previous
//
#include <hip/hip_runtime.h>
#include <cstdint>
#include <cstddef>

// Problem constants (B=8192, P=8192, F=256; SIGMA=1 -> denom = 2)
#define B_ROWS 8192
#define P_ROWS 8192
#define FDIM   256

// Geometry: block = 4 waves = 128 M-rows x 64 N-protos, ONE barrier per
// block. A lives in registers (per wave: 32 rows x K=256 = 64 VGPR, loaded
// once; divergence amortized). B tile (64 protos x K=256 = 32 KiB) is staged
// to LDS once via global_load_lds (1 KB contiguous per wave-instr -> fully
// coalesced; round-2 lesson: per-lane divergent B loads collapse on the
// memory pipe). XOR bank swizzle + column permute applied on the GLOBAL
// source address (LDS dest of global_load_lds stays lane-ordered).
#define MB     128
#define NB     64
#define MBLKS  (B_ROWS / MB)    // 64
#define NBLKS  (P_ROWS / NB)    // 128
#define NBLK   (MBLKS * NBLKS)  // 8192

typedef __bf16  bf16x8  __attribute__((ext_vector_type(8)));
typedef float   floatx4 __attribute__((ext_vector_type(4)));

// round-to-nearest-even fp32 -> bf16 (inputs are finite Gaussians, no NaN path)
__device__ __forceinline__ unsigned short f2bf(float f) {
  unsigned int u = __float_as_uint(f);
  u += 0x7fffu + ((u >> 16) & 1u);
  return (unsigned short)(u >> 16);
}

// async global->LDS, 16B per lane. LDS dest is wave-uniform base + lane*16.
__device__ __forceinline__ void async16(const void* g, void* l) {
  __builtin_amdgcn_global_load_lds(
      (const __attribute__((address_space(1))) void*)g,
      (__attribute__((address_space(3))) void*)l,
      16, 0, 0);
}

// ---------------------------------------------------------------------------
// Pre-pass: convert x / prototypes to bf16 planes in ws, compute fp32 row
// norms. One wave per row (64 lanes x float4 = 256 elems).
// ---------------------------------------------------------------------------
__global__ void __launch_bounds__(64) prep_kernel(
    const float* __restrict__ x, const float* __restrict__ p,
    unsigned short* __restrict__ xbf, unsigned short* __restrict__ pbf,
    float* __restrict__ x2, float* __restrict__ p2) {
  const int row  = blockIdx.x;
  const int lane = threadIdx.x;

  const float* src;
  unsigned short* dst;
  float* nrm;
  int r;
  if (row < B_ROWS) { src = x; dst = xbf; nrm = x2; r = row; }
  else              { src = p; dst = pbf; nrm = p2; r = row - B_ROWS; }

  const float4 v = *reinterpret_cast<const float4*>(src + (size_t)r * FDIM + lane * 4);
  float s = v.x * v.x + v.y * v.y + v.z * v.z + v.w * v.w;
  #pragma unroll
  for (int o = 32; o > 0; o >>= 1) s += __shfl_down(s, o);
  if (lane == 0) nrm[r] = s;

  ushort4 pk;
  pk.x = f2bf(v.x); pk.y = f2bf(v.y); pk.z = f2bf(v.z); pk.w = f2bf(v.w);
  *reinterpret_cast<ushort4*>(dst + (size_t)r * FDIM + lane * 4) = pk;
}

// ---------------------------------------------------------------------------
// Main kernel.
//
// B LDS layout (verified round 1): proto-row r (512 B = 32 chunks of 16B);
// chunk slot c holds GLOBAL K-chunk (c&24)|((c^r)&7) [XOR swizzle ->
// ds_read_b128 is 2-way bank-aliased = free], and row r holds tile-proto
// 4*(r&15) + (r>>4) [permute -> lane lm owns 4 contiguous output cols ->
// float4 nt stores, float4 p2 load].
//
// A fragments (verified round 2): lane (lm,q) of wave w holds rows
// M0+w*32+{lm,16+lm}, k-bytes [kw*64 + q*16, +16) -- direct 16B global
// loads, once per block, overlapped with the staging drain.
//
// Sync: stage B (8 async16/thread) -> issue A loads -> vmcnt(0) -> s_barrier.
// That is the ONLY barrier; afterwards waves drift freely through
// ds_read/MFMA/epilogue. 8192 blocks stream through the CUs so drains of one
// block overlap compute/epilogue of resident neighbors.
// ---------------------------------------------------------------------------
__global__ void __launch_bounds__(256, 3) gauss_kernel(
    const unsigned short* __restrict__ xbf, const unsigned short* __restrict__ pbf,
    const float* __restrict__ x2, const float* __restrict__ p2,
    float* __restrict__ out) {
  __shared__ __align__(16) unsigned short lds_b[NB * FDIM];  // 32 KiB

  const int t    = threadIdx.x;
  const int lane = t & 63;
  const int w    = t >> 6;        // wave 0..3
  const int lm   = lane & 15;
  const int q    = lane >> 4;     // 0..3
  const int s3   = lm & 7;        // XOR swizzle bits

  // XCD-chunked remap (8192 blocks, %8==0, bijective): XCD x owns N-tiles
  // [16x, 16x+16), M fastest -> per-XCD B slice = 1024 protos = 512 KB,
  // L2-resident across the 64-block M sweep.
  const int f   = blockIdx.x;
  const int xcd = f & 7;
  const int idx = f >> 3;               // 0..1023
  const int bm  = idx & 63;             // M-band, fastest
  const int bn  = xcd * 16 + (idx >> 6);
  const int M0  = bm * MB + w * 32;     // this wave's 32-row slab
  const int N0  = bn * NB;

  // ---- B staging: 2048 chunks of 16B, 8 per thread (coalesced) ----
  #pragma unroll
  for (int I = 0; I < 8; ++I) {
    const int L = I * 256 + t;                   // 0..2047
    const int r = L >> 5;                        // LDS proto-row 0..63
    const int c = L & 31;                        // LDS chunk slot
    const int g = (c & 24) | ((c ^ r) & 7);      // global K-chunk for slot c
    const int pl = 4 * (r & 15) + (r >> 4);      // permuted proto-in-tile
    async16(pbf + (size_t)(N0 + pl) * FDIM + g * 8,
            (char*)lds_b + (size_t)L * 16);
  }

  // ---- A fragments in registers (overlap with staging drain) ----
  const unsigned short* aBase = xbf + (size_t)(M0 + lm) * FDIM + q * 8;
  bf16x8 af[2][8];
  #pragma unroll
  for (int i = 0; i < 2; ++i)
    #pragma unroll
    for (int kw = 0; kw < 8; ++kw)
      af[i][kw] = *(const bf16x8*)(aBase + (size_t)i * 16 * FDIM + kw * 32);

  floatx4 x2v[2];
  #pragma unroll
  for (int i = 0; i < 2; ++i)
    x2v[i] = *(const floatx4*)&x2[M0 + i * 16 + q * 4];
  const floatx4 p2r = *(const floatx4*)&p2[N0 + 4 * lm];

  asm volatile("s_waitcnt vmcnt(0)" ::: "memory");
  __builtin_amdgcn_s_barrier();    // the only barrier in the kernel

  // ---- compute: 8 K-windows x (4 ds_read_b128 + 8 MFMA) ----
  floatx4 acc[2][4] = {};
  #pragma unroll
  for (int kw = 0; kw < 8; ++kw) {
    const int cc = (kw * 4 + q) ^ s3;            // swizzled 16B chunk
    bf16x8 bfr[4];
    #pragma unroll
    for (int j = 0; j < 4; ++j)
      bfr[j] = *(const bf16x8*)&lds_b[(j * 16 + lm) * FDIM + cc * 8];
    #pragma unroll
    for (int i = 0; i < 2; ++i)
      #pragma unroll
      for (int j = 0; j < 4; ++j)
        acc[i][j] = __builtin_amdgcn_mfma_f32_16x16x32_bf16(af[i][kw], bfr[j], acc[i][j], 0, 0, 0);
  }

  // ---- epilogue: d2 -> exp(-sqrt(d2)/2), float4 nt stores ----
  #pragma unroll
  for (int i = 0; i < 2; ++i) {
    #pragma unroll
    for (int v = 0; v < 4; ++v) {
      floatx4 res;
      #pragma unroll
      for (int j = 0; j < 4; ++j) {
        float d2 = x2v[i][v] + p2r[j] - 2.0f * acc[i][j][v];
        d2 = fmaxf(d2, 0.0f);
        res[j] = __expf(-0.5f * sqrtf(d2));      // denom = 2*sigma^2 = 2
      }
      __builtin_nontemporal_store(
          res, (floatx4*)(out + (size_t)(M0 + i * 16 + q * 4 + v) * P_ROWS + N0 + 4 * lm));
    }
  }
}

// ---------------------------------------------------------------------------
extern "C" void kernel_launch(void* const* d_in, const int* in_sizes, int n_in,
                              void* d_out, int out_size, void* d_ws, size_t ws_size,
                              hipStream_t stream) {
  const float* x = (const float*)d_in[0];
  const float* p = (const float*)d_in[1];
  float* out = (float*)d_out;

  // ws layout: xbf (4 MiB) | pbf (4 MiB) | x2 (32 KiB) | p2 (32 KiB)
  char* ws = (char*)d_ws;
  unsigned short* xbf = (unsigned short*)ws;
  unsigned short* pbf = (unsigned short*)(ws + (size_t)B_ROWS * FDIM * 2);
  float* x2 = (float*)(ws + (size_t)(B_ROWS + P_ROWS) * FDIM * 2);
  float* p2 = x2 + B_ROWS;

  prep_kernel<<<dim3(B_ROWS + P_ROWS), dim3(64), 0, stream>>>(x, p, xbf, pbf, x2, p2);

  gauss_kernel<<<dim3(NBLK), dim3(256), 0, stream>>>(xbf, pbf, x2, p2, out);
}

// Round 6
// 311.262 us; speedup vs baseline: 1.2494x; 1.0178x over previous
//
#include <hip/hip_runtime.h>
#include <cstdint>
#include <cstddef>

// Problem constants (B=8192, P=8192, F=256; SIGMA=1 -> denom = 2)
#define B_ROWS 8192
#define P_ROWS 8192
#define FDIM   256

// Structure: best-known R0 geometry (128x128 tile, coalesced global_load_lds
// for BOTH operands, XOR bank swizzle, B column permute, nt float4 stores)
// with two fixes aimed at the measured latency-boundness:
//  * 2-phase software pipeline: double-buffered LDS, stage(s+1) issued
//    BEFORE compute(s) -> the end-of-step __syncthreads drain (vmcnt) is
//    hidden under ~1300 cyc of ds_read+MFMA instead of exposed (R0 staged
//    after the barrier and drained immediately).
//  * 512-thread blocks (8 waves): 64 KiB LDS -> 2 blocks/CU = 16 waves/CU,
//    per-block latency halved vs 4-wave blocks with the same LDS.
// (Round-5 bench was an infra failure -- "container failed twice", no
// correctness/perf verdict -- so this resubmits the identical experiment.)
#define BM 128
#define BN 128
#define BK 64
#define NSTEP (FDIM / BK)   // 4 K-steps

typedef __bf16  bf16x8  __attribute__((ext_vector_type(8)));
typedef float   floatx4 __attribute__((ext_vector_type(4)));

// round-to-nearest-even fp32 -> bf16 (inputs are finite Gaussians, no NaN path)
__device__ __forceinline__ unsigned short f2bf(float f) {
  unsigned int u = __float_as_uint(f);
  u += 0x7fffu + ((u >> 16) & 1u);
  return (unsigned short)(u >> 16);
}

// async global->LDS, 16B per lane. LDS dest is wave-uniform base + lane*16.
__device__ __forceinline__ void async16(const void* g, void* l) {
  __builtin_amdgcn_global_load_lds(
      (const __attribute__((address_space(1))) void*)g,
      (__attribute__((address_space(3))) void*)l,
      16, 0, 0);
}

// ---------------------------------------------------------------------------
// Pre-pass: convert x / prototypes to bf16 planes in ws, compute fp32 row
// norms. One wave per row (64 lanes x float4 = 256 elems).
// ---------------------------------------------------------------------------
__global__ void __launch_bounds__(64) prep_kernel(
    const float* __restrict__ x, const float* __restrict__ p,
    unsigned short* __restrict__ xbf, unsigned short* __restrict__ pbf,
    float* __restrict__ x2, float* __restrict__ p2) {
  const int row  = blockIdx.x;
  const int lane = threadIdx.x;

  const float* src;
  unsigned short* dst;
  float* nrm;
  int r;
  if (row < B_ROWS) { src = x; dst = xbf; nrm = x2; r = row; }
  else              { src = p; dst = pbf; nrm = p2; r = row - B_ROWS; }

  const float4 v = *reinterpret_cast<const float4*>(src + (size_t)r * FDIM + lane * 4);
  float s = v.x * v.x + v.y * v.y + v.z * v.z + v.w * v.w;
  #pragma unroll
  for (int o = 32; o > 0; o >>= 1) s += __shfl_down(s, o);
  if (lane == 0) nrm[r] = s;

  ushort4 pk;
  pk.x = f2bf(v.x); pk.y = f2bf(v.y); pk.z = f2bf(v.z); pk.w = f2bf(v.w);
  *reinterpret_cast<ushort4*>(dst + (size_t)r * FDIM + lane * 4) = pk;
}

// ---------------------------------------------------------------------------
// Main kernel. 8 waves: wave w -> (wr = w>>1) 32-row M slab, (wc = w&1)
// 64-col N slab of the 128x128 tile.
//
// LDS layouts (verified in rounds 0-3):
//  A: row r holds global K-chunks; slot c stores chunk c^(r&7) (XOR swizzle
//     -> ds_read_b128 2-way bank-aliased = free).
//  B: LDS row r holds prototype pr = (r&64) + 4*(r&15) + ((r>>4)&3) of the
//     128-proto tile (bijective permute -> lane lm's accumulator j is proto
//     wc*64 + 4*lm + j -> contiguous float4 stores), same XOR chunk swizzle.
// Both permutations applied on the GLOBAL source address; the LDS dest of
// global_load_lds stays strictly lane-ordered (L = I*512 + t).
//
// Pipeline: stage(0) -> sync; for s: stage(s+1, other buf) issued FIRST,
// compute(s), __syncthreads() (vmcnt drain hidden under compute). 5 barriers
// per block, none with exposed latency.
// ---------------------------------------------------------------------------
__global__ void __launch_bounds__(512, 4) gauss_kernel(
    const unsigned short* __restrict__ xbf, const unsigned short* __restrict__ pbf,
    const float* __restrict__ x2, const float* __restrict__ p2,
    float* __restrict__ out) {
  __shared__ __align__(16) unsigned short lds_a[2][BM * BK];  // 2 x 16 KiB
  __shared__ __align__(16) unsigned short lds_b[2][BN * BK];  // 2 x 16 KiB

  const int t    = threadIdx.x;
  const int lane = t & 63;
  const int w    = t >> 6;        // wave 0..7
  const int wr   = w >> 1;        // 0..3: 32-row M slab
  const int wc   = w & 1;         // 0..1: 64-col N slab
  const int lm   = lane & 15;
  const int q    = lane >> 4;     // 0..3
  const int sx   = lane & 7;      // XOR swizzle bits (== row&7 for all reads)

  // XCD-chunked remap (4096 blocks, %8==0, bijective): XCD x owns M-tile
  // band [8x, 8x+8), M fastest within the band.
  const int f   = blockIdx.x;
  const int xcd = f & 7;
  const int idx = f >> 3;                   // 0..511
  const int M0  = (xcd * 8 + (idx & 7)) * BM;
  const int N0  = (idx >> 3) * BN;

  // ---- staging offsets: 1024 16B chunks per operand per K-step,
  //      2 per thread per operand (I = 0,1) ----
  unsigned int aOff[2], bOff[2], lOff[2];
  #pragma unroll
  for (int I = 0; I < 2; ++I) {
    const int L = I * 512 + t;                   // 0..1023
    const int r = L >> 3;                        // LDS row 0..127
    const int c = L & 7;                         // chunk slot in row
    const int g = c ^ (r & 7);                   // global chunk for slot c
    aOff[I] = (unsigned int)(((M0 + r) * FDIM + g * 8) * 2);   // bytes
    const int pr = (r & 64) + 4 * (r & 15) + ((r >> 4) & 3);   // proto permute
    bOff[I] = (unsigned int)(((N0 + pr) * FDIM + g * 8) * 2);  // bytes
    lOff[I] = (unsigned int)(L * 16);                           // bytes
  }
  const char* xB = (const char*)xbf;
  const char* pB = (const char*)pbf;

  // epilogue inputs (issued early; drained by the prologue sync)
  floatx4 x2v[2];
  #pragma unroll
  for (int i = 0; i < 2; ++i)
    x2v[i] = *(const floatx4*)&x2[M0 + wr * 32 + i * 16 + q * 4];
  const floatx4 p2r = *(const floatx4*)&p2[N0 + wc * 64 + 4 * lm];

  // ---- prologue: stage step 0 into buffer 0 ----
  #pragma unroll
  for (int I = 0; I < 2; ++I) async16(xB + aOff[I], (char*)&lds_a[0][0] + lOff[I]);
  #pragma unroll
  for (int I = 0; I < 2; ++I) async16(pB + bOff[I], (char*)&lds_b[0][0] + lOff[I]);
  __syncthreads();

  floatx4 acc[2][4] = {};

  #pragma unroll
  for (int s = 0; s < NSTEP; ++s) {
    const int b = s & 1;

    if (s + 1 < NSTEP) {   // issue next step's staging BEFORE compute
      const unsigned int ko = (unsigned int)((s + 1) * BK * 2);
      #pragma unroll
      for (int I = 0; I < 2; ++I)
        async16(xB + aOff[I] + ko, (char*)&lds_a[b ^ 1][0] + lOff[I]);
      #pragma unroll
      for (int I = 0; I < 2; ++I)
        async16(pB + bOff[I] + ko, (char*)&lds_b[b ^ 1][0] + lOff[I]);
    }

    #pragma unroll
    for (int kk = 0; kk < 2; ++kk) {             // two K=32 windows
      const int slot = ((kk * 4 + q) ^ sx) * 8;  // swizzled 16B chunk
      bf16x8 af[2], bfr[4];
      #pragma unroll
      for (int i = 0; i < 2; ++i)
        af[i] = *(const bf16x8*)&lds_a[b][(wr * 32 + i * 16 + lm) * BK + slot];
      #pragma unroll
      for (int j = 0; j < 4; ++j)
        bfr[j] = *(const bf16x8*)&lds_b[b][(wc * 64 + j * 16 + lm) * BK + slot];
      #pragma unroll
      for (int i = 0; i < 2; ++i)
        #pragma unroll
        for (int j = 0; j < 4; ++j)
          acc[i][j] = __builtin_amdgcn_mfma_f32_16x16x32_bf16(af[i], bfr[j], acc[i][j], 0, 0, 0);
    }

    if (s + 1 < NSTEP) __syncthreads();  // vmcnt drain hidden under compute
  }

  // ---- epilogue: d2 -> exp(-sqrt(d2)/2), float4 nt stores ----
  #pragma unroll
  for (int i = 0; i < 2; ++i) {
    #pragma unroll
    for (int v = 0; v < 4; ++v) {
      floatx4 res;
      #pragma unroll
      for (int j = 0; j < 4; ++j) {
        float d2 = x2v[i][v] + p2r[j] - 2.0f * acc[i][j][v];
        d2 = fmaxf(d2, 0.0f);
        res[j] = __expf(-0.5f * sqrtf(d2));      // denom = 2*sigma^2 = 2
      }
      __builtin_nontemporal_store(
          res, (floatx4*)(out + (size_t)(M0 + wr * 32 + i * 16 + q * 4 + v) * P_ROWS
                          + N0 + wc * 64 + 4 * lm));
    }
  }
}

// ---------------------------------------------------------------------------
extern "C" void kernel_launch(void* const* d_in, const int* in_sizes, int n_in,
                              void* d_out, int out_size, void* d_ws, size_t ws_size,
                              hipStream_t stream) {
  const float* x = (const float*)d_in[0];
  const float* p = (const float*)d_in[1];
  float* out = (float*)d_out;

  // ws layout: xbf (4 MiB) | pbf (4 MiB) | x2 (32 KiB) | p2 (32 KiB)
  char* ws = (char*)d_ws;
  unsigned short* xbf = (unsigned short*)ws;
  unsigned short* pbf = (unsigned short*)(ws + (size_t)B_ROWS * FDIM * 2);
  float* x2 = (float*)(ws + (size_t)(B_ROWS + P_ROWS) * FDIM * 2);
  float* p2 = x2 + B_ROWS;

  prep_kernel<<<dim3(B_ROWS + P_ROWS), dim3(64), 0, stream>>>(x, p, xbf, pbf, x2, p2);

  gauss_kernel<<<dim3((B_ROWS / BM) * (P_ROWS / BN)), dim3(512), 0, stream>>>(
      xbf, pbf, x2, p2, out);
}